// Round 2
// baseline (1450.766 us; speedup 1.0000x reference)
//
#include <hip/hip_runtime.h>
#include <math.h>

#define TPB 1024
#define ELB 64              // batch elements per block (= lanes per wave)

// ---- LDS float offsets ----
#define XS  132             // x/att/out row stride (33 quads, odd -> 8-pass optimal)
#define ZSS 180             // z row stride (45 quads, odd)
#define HS  132             // h row stride
#define OFF_X 0             // [64][132]  x -> attended -> out
#define OFF_Z 8448          // [64][180]  z chunks; reused as h [64][132]
#define SMEM_FLOATS (8448 + 11520)
#define SMEM_BYTES  (SMEM_FLOATS * 4)   // 79872 B

// ---- Cl(3,0) pair tables (blade order 1,e1,e2,e3,e12,e13,e23,e123) ----
// 64 products x[i]*xr[k] -> 44 (path,j) slots with sign (verified round 1)
constexpr int ZI[64] = {
    0,0,0,0,0,0,0,0,  1,1,1,1,1,1,1,1,  2,2,2,2,2,2,2,2,  4,4,4,4,4,4,4,4,
    3,3,3,3,3,3,3,3,  5,5,5,5,5,5,5,5,  6,6,6,6,6,6,6,6,  7,7,7,7,7,7,7,7};
constexpr int ZK[64] = {
    0,1,2,4,3,5,6,7,  0,1,2,4,3,5,6,7,  0,1,2,4,3,5,6,7,  0,1,2,4,3,5,6,7,
    0,1,2,4,3,5,6,7,  0,1,2,4,3,5,6,7,  0,1,2,4,3,5,6,7,  0,1,2,4,3,5,6,7};
constexpr int ZSl[64] = {
    0,1,2,4,3,5,6,7,
    9,8,15,13,16,14,21,20,
    10,15,8,12,17,21,14,19,
    29,24,23,22,35,34,33,28,
    11,16,17,21,8,12,13,18,
    30,25,35,34,23,22,32,27,
    31,35,25,33,24,32,22,26,
    43,42,41,39,40,38,37,36};
constexpr int ZG[64] = {   // 1 = +, 0 = -
    1,1,1,1,1,1,1,1,
    1,1,1,1,1,1,1,1,
    1,0,1,0,1,0,1,0,
    1,0,1,0,1,0,1,0,
    1,0,0,1,1,0,0,1,
    1,0,0,1,1,0,0,1,
    1,1,0,0,1,1,0,0,
    1,1,0,0,1,1,0,0};
// slot -> path index (into w_gp[...,20]) and output blade j
constexpr int CP[44] = {
    0, 1,1,1, 2,2,2, 3,
    4, 5,5,5, 6,6,6, 7,7,7, 8,8,8, 9,
    10, 11,11,11, 12,12,12, 13,13,13, 14,14,14, 15,
    16, 17,17,17, 18,18,18, 19};
constexpr int CJ[44] = {
    0, 1,2,3, 4,5,6, 7,
    0, 1,2,3, 1,2,3, 4,5,6, 4,5,6, 7,
    0, 1,2,3, 1,2,3, 4,5,6, 4,5,6, 7,
    0, 1,2,3, 4,5,6, 7};

__device__ __forceinline__ float sigmoidf_(float v) {
    return __builtin_amdgcn_rcpf(1.0f + __expf(-v));
}

__global__ __launch_bounds__(TPB, 4)
void mv_block_kernel(const float* __restrict__ xg,
                     const float* __restrict__ w_right,
                     const float* __restrict__ a_norm,
                     const float* __restrict__ w_gp,
                     const float* __restrict__ w_left,
                     const float* __restrict__ b_left,
                     const float* __restrict__ w_up,
                     const float* __restrict__ b_up,
                     const float* __restrict__ a_act,
                     const float* __restrict__ b_act,
                     const float* __restrict__ w_down,
                     const float* __restrict__ b_down,
                     float* __restrict__ outg)
{
    extern __shared__ float sm[];
    const int t = threadIdx.x;
    const int b = t & 63;                                  // lane = batch element in group
    const int m = __builtin_amdgcn_readfirstlane(t >> 6);  // wave = output channel (uniform!)
    const int g = blockIdx.x;

    // ---------- stage x (coalesced global, dense) ----------
    {
        const float4* xs = (const float4*)xg + (size_t)g * 2048;
        #pragma unroll
        for (int r = 0; r < 2; ++r) {
            const int idx = r * 1024 + t;
            const float4 v = xs[idx];
            const int el = idx >> 5, off = idx & 31;
            *(float4*)&sm[OFF_X + el * XS + off * 4] = v;
        }
    }
    __syncthreads();

    // ---------- phase A: right-linear + left-linear (weights via s_load) ----------
    float xr[8] = {0,0,0,0,0,0,0,0};
    float lf[8] = {0,0,0,0,0,0,0,0};
    {
        const float* sx = &sm[OFF_X + b * XS];
        #pragma unroll
        for (int n = 0; n < 16; ++n) {
            const float4 xa = *(const float4*)&sx[n*8];
            const float4 xb = *(const float4*)&sx[n*8+4];
            const float4 w  = *(const float4*)&w_right[(m*16+n)*4];   // uniform
            const float4 v  = *(const float4*)&w_left [(m*16+n)*4];   // uniform
            xr[0] += xa.x*w.x; xr[1] += xa.y*w.y; xr[2] += xa.z*w.y; xr[3] += xa.w*w.y;
            xr[4] += xb.x*w.z; xr[5] += xb.y*w.z; xr[6] += xb.z*w.z; xr[7] += xb.w*w.w;
            lf[0] += xa.x*v.x; lf[1] += xa.y*v.y; lf[2] += xa.z*v.y; lf[3] += xa.w*v.y;
            lf[4] += xb.x*v.z; lf[5] += xb.y*v.z; lf[6] += xb.z*v.z; lf[7] += xb.w*v.w;
        }
    }

    // ---------- phase B: gated per-grade normalization (xr stays in registers) ----------
    {
        const float q0 = xr[0]*xr[0];
        const float q1 = xr[1]*xr[1] + xr[2]*xr[2] + xr[3]*xr[3];
        const float q2 = xr[4]*xr[4] + xr[5]*xr[5] + xr[6]*xr[6];
        const float q3 = xr[7]*xr[7];
        const float4 an = *(const float4*)&a_norm[m*4];               // uniform
        const float i0 = __builtin_amdgcn_rcpf(sigmoidf_(an.x)*(sqrtf(q0)-1.0f)+1.0f + 1e-6f);
        const float i1 = __builtin_amdgcn_rcpf(sigmoidf_(an.y)*(sqrtf(q1)-1.0f)+1.0f + 1e-6f);
        const float i2 = __builtin_amdgcn_rcpf(sigmoidf_(an.z)*(sqrtf(q2)-1.0f)+1.0f + 1e-6f);
        const float i3 = __builtin_amdgcn_rcpf(sigmoidf_(an.w)*(sqrtf(q3)-1.0f)+1.0f + 1e-6f);
        xr[0]*=i0; xr[1]*=i1; xr[2]*=i1; xr[3]*=i1;
        xr[4]*=i2; xr[5]*=i2; xr[6]*=i2; xr[7]*=i3;
    }

    // ---------- phase C: geometric product; wave m forms z for n=m, contraction over 4-n chunks ----------
    float gp[8] = {0,0,0,0,0,0,0,0};
    #pragma unroll
    for (int c = 0; c < 4; ++c) {
        if ((m >> 2) == c) {            // wave-uniform branch: this wave writes its z
            const float* px = &sm[OFF_X + b * XS + m * 8];
            float xv[8];
            { const float4 u = *(const float4*)px;     xv[0]=u.x; xv[1]=u.y; xv[2]=u.z; xv[3]=u.w; }
            { const float4 u = *(const float4*)(px+4); xv[4]=u.x; xv[5]=u.y; xv[6]=u.z; xv[7]=u.w; }
            float z[44];
            #pragma unroll
            for (int s = 0; s < 44; ++s) z[s] = 0.0f;
            #pragma unroll
            for (int e = 0; e < 64; ++e) {
                const float p = xv[ZI[e]] * xr[ZK[e]];
                if (ZG[e]) z[ZSl[e]] += p; else z[ZSl[e]] -= p;
            }
            float* pz = &sm[OFF_Z + b * ZSS + (m & 3) * 44];
            #pragma unroll
            for (int s = 0; s < 44; s += 4)
                *(float4*)&pz[s] = make_float4(z[s], z[s+1], z[s+2], z[s+3]);
        }
        __syncthreads();
        #pragma unroll
        for (int nl = 0; nl < 4; ++nl) {
            const int n = c * 4 + nl;
            const float* pw = &w_gp[(m*16+n)*20];                     // uniform
            float wg[20];
            #pragma unroll
            for (int s = 0; s < 20; s += 4) {
                const float4 u = *(const float4*)&pw[s];
                wg[s]=u.x; wg[s+1]=u.y; wg[s+2]=u.z; wg[s+3]=u.w;
            }
            const float* pz = &sm[OFF_Z + b * ZSS + nl * 44];
            float zr[44];
            #pragma unroll
            for (int s = 0; s < 44; s += 4) {
                const float4 u = *(const float4*)&pz[s];
                zr[s]=u.x; zr[s+1]=u.y; zr[s+2]=u.z; zr[s+3]=u.w;
            }
            #pragma unroll
            for (int s = 0; s < 44; ++s) gp[CJ[s]] += wg[CP[s]] * zr[s];
        }
        __syncthreads();
    }

    // ---------- attended = (left + b_left + gp) / sqrt(2); overwrite X with att ----------
    float att[8];
    lf[0] += b_left[m];                                               // uniform
    #pragma unroll
    for (int i = 0; i < 8; ++i) att[i] = (lf[i] + gp[i]) * 0.70710678118654752f;
    *(float4*)&sm[OFF_X + b * XS + m * 8]     = make_float4(att[0],att[1],att[2],att[3]);
    *(float4*)&sm[OFF_X + b * XS + m * 8 + 4] = make_float4(att[4],att[5],att[6],att[7]);
    __syncthreads();

    // ---------- phase D: up (wave handles m2 = q*16+m, q=0..3) ----------
    float h[4][8];
    #pragma unroll
    for (int q = 0; q < 4; ++q)
        #pragma unroll
        for (int i = 0; i < 8; ++i) h[q][i] = 0.0f;
    {
        const float* sa = &sm[OFF_X + b * XS];
        #pragma unroll
        for (int n = 0; n < 16; ++n) {
            const float4 aa = *(const float4*)&sa[n*8];
            const float4 ab = *(const float4*)&sa[n*8+4];
            #pragma unroll
            for (int q = 0; q < 4; ++q) {
                const float4 w = *(const float4*)&w_up[(((q*16+m)*16)+n)*4];  // uniform
                h[q][0]+=aa.x*w.x; h[q][1]+=aa.y*w.y; h[q][2]+=aa.z*w.y; h[q][3]+=aa.w*w.y;
                h[q][4]+=ab.x*w.z; h[q][5]+=ab.y*w.z; h[q][6]+=ab.z*w.z; h[q][7]+=ab.w*w.w;
            }
        }
    }
    // silu gates
    #pragma unroll
    for (int q = 0; q < 4; ++q) {
        const int m2 = q*16 + m;
        h[q][0] += b_up[m2];                                          // uniform
        const float inv0 = h[q][0];
        const float inv1 = h[q][1]*h[q][1] + h[q][2]*h[q][2] + h[q][3]*h[q][3];
        const float inv2 = h[q][4]*h[q][4] + h[q][5]*h[q][5] + h[q][6]*h[q][6];
        const float inv3 = h[q][7]*h[q][7];
        const float4 a4 = *(const float4*)&a_act[m2*4];               // uniform
        const float4 b4 = *(const float4*)&b_act[m2*4];               // uniform
        const float g0 = sigmoidf_(a4.x*inv0 + b4.x);
        const float g1 = sigmoidf_(a4.y*inv1 + b4.y);
        const float g2 = sigmoidf_(a4.z*inv2 + b4.z);
        const float g3 = sigmoidf_(a4.w*inv3 + b4.w);
        h[q][0]*=g0; h[q][1]*=g1; h[q][2]*=g1; h[q][3]*=g1;
        h[q][4]*=g2; h[q][5]*=g2; h[q][6]*=g2; h[q][7]*=g3;
    }

    // ---------- down: 4 chunks of 16 m2; h bounced through LDS (reuses Z region) ----------
    float oacc[8] = {0,0,0,0,0,0,0,0};
    #pragma unroll
    for (int q = 0; q < 4; ++q) {
        if (q) __syncthreads();         // protect H region from previous chunk's reads
        float* ph = &sm[OFF_Z + b * HS + m * 8];
        *(float4*)&ph[0] = make_float4(h[q][0], h[q][1], h[q][2], h[q][3]);
        *(float4*)&ph[4] = make_float4(h[q][4], h[q][5], h[q][6], h[q][7]);
        __syncthreads();
        #pragma unroll
        for (int s = 0; s < 16; ++s) {
            const float* pr = &sm[OFF_Z + b * HS + s * 8];
            const float4 ha = *(const float4*)&pr[0];
            const float4 hb = *(const float4*)&pr[4];
            const float4 w  = *(const float4*)&w_down[(m*64 + q*16 + s)*4];   // uniform
            oacc[0]+=ha.x*w.x; oacc[1]+=ha.y*w.y; oacc[2]+=ha.z*w.y; oacc[3]+=ha.w*w.y;
            oacc[4]+=hb.x*w.z; oacc[5]+=hb.y*w.z; oacc[6]+=hb.z*w.z; oacc[7]+=hb.w*w.w;
        }
    }

    // ---------- epilogue: out = attended + down + b_down; bounce via LDS for dense stores ----------
    oacc[0] += b_down[m];                                             // uniform
    float o[8];
    #pragma unroll
    for (int i = 0; i < 8; ++i) o[i] = att[i] + oacc[i];
    *(float4*)&sm[OFF_X + b * XS + m * 8]     = make_float4(o[0],o[1],o[2],o[3]);
    *(float4*)&sm[OFF_X + b * XS + m * 8 + 4] = make_float4(o[4],o[5],o[6],o[7]);
    __syncthreads();
    {
        float4* og = (float4*)outg + (size_t)g * 2048;
        #pragma unroll
        for (int r = 0; r < 2; ++r) {
            const int idx = r * 1024 + t;
            const int el = idx >> 5, off = idx & 31;
            og[idx] = *(const float4*)&sm[OFF_X + el * XS + off * 4];
        }
    }
}

extern "C" void kernel_launch(void* const* d_in, const int* in_sizes, int n_in,
                              void* d_out, int out_size, void* d_ws, size_t ws_size,
                              hipStream_t stream) {
    const float* x       = (const float*)d_in[0];
    const float* w_right = (const float*)d_in[1];
    const float* a_norm  = (const float*)d_in[2];
    const float* w_gp    = (const float*)d_in[3];
    const float* w_left  = (const float*)d_in[4];
    const float* b_left  = (const float*)d_in[5];
    const float* w_up    = (const float*)d_in[6];
    const float* b_up    = (const float*)d_in[7];
    const float* a_act   = (const float*)d_in[8];
    const float* b_act   = (const float*)d_in[9];
    const float* w_down  = (const float*)d_in[10];
    const float* b_down  = (const float*)d_in[11];
    float* out = (float*)d_out;

    const int B = in_sizes[0] / 128;        // 65536
    const int ngroups = B / ELB;            // 1024

    (void)hipFuncSetAttribute((const void*)mv_block_kernel,
                              hipFuncAttributeMaxDynamicSharedMemorySize, SMEM_BYTES);
    mv_block_kernel<<<ngroups, TPB, SMEM_BYTES, stream>>>(
        x, w_right, a_norm, w_gp, w_left, b_left,
        w_up, b_up, a_act, b_act, w_down, b_down, out);
}

// Round 3
// 887.360 us; speedup vs baseline: 1.6349x; 1.6349x over previous
//
#include <hip/hip_runtime.h>
#include <math.h>

#define TPB 1024

// ---- LDS float offsets (all element-strides == 4 mod 32: conflict-minimal b128) ----
#define XS   132            // x/att/out el-stride
#define ZES  356            // z el-stride (8 nl * 44 + 4 pad)
#define HES  260            // h el-stride (32 m2 * 8 + 4 pad)
#define OFF_X 0             // [64][132]
#define OFF_Z 8448          // [64][356] z chunks; reused as h [64][260]
#define SMEM_FLOATS (8448 + 22784)      // 31232 floats = 124928 B
#define SMEM_BYTES  (SMEM_FLOATS * 4)

// ---- Cl(3,0) pair tables (blade order 1,e1,e2,e3,e12,e13,e23,e123) ----
// 64 products x[i]*xr[k] -> 44 (path,j) slots with sign (verified round 1)
constexpr int ZI[64] = {
    0,0,0,0,0,0,0,0,  1,1,1,1,1,1,1,1,  2,2,2,2,2,2,2,2,  4,4,4,4,4,4,4,4,
    3,3,3,3,3,3,3,3,  5,5,5,5,5,5,5,5,  6,6,6,6,6,6,6,6,  7,7,7,7,7,7,7,7};
constexpr int ZK[64] = {
    0,1,2,4,3,5,6,7,  0,1,2,4,3,5,6,7,  0,1,2,4,3,5,6,7,  0,1,2,4,3,5,6,7,
    0,1,2,4,3,5,6,7,  0,1,2,4,3,5,6,7,  0,1,2,4,3,5,6,7,  0,1,2,4,3,5,6,7};
constexpr int ZSl[64] = {
    0,1,2,4,3,5,6,7,
    9,8,15,13,16,14,21,20,
    10,15,8,12,17,21,14,19,
    29,24,23,22,35,34,33,28,
    11,16,17,21,8,12,13,18,
    30,25,35,34,23,22,32,27,
    31,35,25,33,24,32,22,26,
    43,42,41,39,40,38,37,36};
constexpr int ZG[64] = {   // 1 = +, 0 = -
    1,1,1,1,1,1,1,1,
    1,1,1,1,1,1,1,1,
    1,0,1,0,1,0,1,0,
    1,0,1,0,1,0,1,0,
    1,0,0,1,1,0,0,1,
    1,0,0,1,1,0,0,1,
    1,1,0,0,1,1,0,0,
    1,1,0,0,1,1,0,0};
// slot -> path index (into w_gp[...,20]) and output blade j
constexpr int CP[44] = {
    0, 1,1,1, 2,2,2, 3,
    4, 5,5,5, 6,6,6, 7,7,7, 8,8,8, 9,
    10, 11,11,11, 12,12,12, 13,13,13, 14,14,14, 15,
    16, 17,17,17, 18,18,18, 19};
constexpr int CJ[44] = {
    0, 1,2,3, 4,5,6, 7,
    0, 1,2,3, 1,2,3, 4,5,6, 4,5,6, 7,
    0, 1,2,3, 1,2,3, 4,5,6, 4,5,6, 7,
    0, 1,2,3, 4,5,6, 7};

__device__ __forceinline__ float sigmoidf_(float v) {
    return __builtin_amdgcn_rcpf(1.0f + __expf(-v));
}

__global__ __launch_bounds__(TPB, 1)
void mv_block_kernel(const float* __restrict__ xg,
                     const float* __restrict__ w_right,
                     const float* __restrict__ a_norm,
                     const float* __restrict__ w_gp,
                     const float* __restrict__ w_left,
                     const float* __restrict__ b_left,
                     const float* __restrict__ w_up,
                     const float* __restrict__ b_up,
                     const float* __restrict__ a_act,
                     const float* __restrict__ b_act,
                     const float* __restrict__ w_down,
                     const float* __restrict__ b_down,
                     float* __restrict__ outg)
{
    extern __shared__ float sm[];
    const int t = threadIdx.x;
    const int b = t & 63;                                  // lane = batch element in group
    const int m = __builtin_amdgcn_readfirstlane(t >> 6);  // wave = output channel (uniform)
    const int g = blockIdx.x;

    // ---------- stage x (coalesced global, dense) ----------
    {
        const float4* xs = (const float4*)xg + (size_t)g * 2048;
        #pragma unroll
        for (int r = 0; r < 2; ++r) {
            const int idx = r * 1024 + t;
            const float4 v = xs[idx];
            const int el = idx >> 5, off = idx & 31;
            *(float4*)&sm[OFF_X + el * XS + off * 4] = v;
        }
    }
    __syncthreads();

    // ---------- phase A: right-linear + left-linear (weights scalar via uniform m) ----------
    float xr[8] = {0,0,0,0,0,0,0,0};
    float lf[8] = {0,0,0,0,0,0,0,0};
    {
        const float* sx = &sm[OFF_X + b * XS];
        #pragma unroll
        for (int n = 0; n < 16; ++n) {
            const float4 xa = *(const float4*)&sx[n*8];
            const float4 xb = *(const float4*)&sx[n*8+4];
            const float4 w  = *(const float4*)&w_right[(m*16+n)*4];   // uniform
            const float4 v  = *(const float4*)&w_left [(m*16+n)*4];   // uniform
            xr[0] += xa.x*w.x; xr[1] += xa.y*w.y; xr[2] += xa.z*w.y; xr[3] += xa.w*w.y;
            xr[4] += xb.x*w.z; xr[5] += xb.y*w.z; xr[6] += xb.z*w.z; xr[7] += xb.w*w.w;
            lf[0] += xa.x*v.x; lf[1] += xa.y*v.y; lf[2] += xa.z*v.y; lf[3] += xa.w*v.y;
            lf[4] += xb.x*v.z; lf[5] += xb.y*v.z; lf[6] += xb.z*v.z; lf[7] += xb.w*v.w;
        }
    }

    // ---------- phase B: gated per-grade normalization (xr stays in registers) ----------
    {
        const float q0 = xr[0]*xr[0];
        const float q1 = xr[1]*xr[1] + xr[2]*xr[2] + xr[3]*xr[3];
        const float q2 = xr[4]*xr[4] + xr[5]*xr[5] + xr[6]*xr[6];
        const float q3 = xr[7]*xr[7];
        const float4 an = *(const float4*)&a_norm[m*4];               // uniform
        const float i0 = __builtin_amdgcn_rcpf(sigmoidf_(an.x)*(sqrtf(q0)-1.0f)+1.0f + 1e-6f);
        const float i1 = __builtin_amdgcn_rcpf(sigmoidf_(an.y)*(sqrtf(q1)-1.0f)+1.0f + 1e-6f);
        const float i2 = __builtin_amdgcn_rcpf(sigmoidf_(an.z)*(sqrtf(q2)-1.0f)+1.0f + 1e-6f);
        const float i3 = __builtin_amdgcn_rcpf(sigmoidf_(an.w)*(sqrtf(q3)-1.0f)+1.0f + 1e-6f);
        xr[0]*=i0; xr[1]*=i1; xr[2]*=i1; xr[3]*=i1;
        xr[4]*=i2; xr[5]*=i2; xr[6]*=i2; xr[7]*=i3;
    }

    // ---------- phase C: geometric product; 2 chunks of 8 n; z streamed in float4s ----------
    float gp[8] = {0,0,0,0,0,0,0,0};
    #pragma unroll
    for (int c = 0; c < 2; ++c) {
        if ((m >> 3) == c) {            // wave-uniform branch: wave m forms z for n = m
            const float* px = &sm[OFF_X + b * XS + m * 8];
            float xv[8];
            { const float4 u = *(const float4*)px;     xv[0]=u.x; xv[1]=u.y; xv[2]=u.z; xv[3]=u.w; }
            { const float4 u = *(const float4*)(px+4); xv[4]=u.x; xv[5]=u.y; xv[6]=u.z; xv[7]=u.w; }
            float z[44];
            #pragma unroll
            for (int s = 0; s < 44; ++s) z[s] = 0.0f;
            #pragma unroll
            for (int e = 0; e < 64; ++e) {
                const float p = xv[ZI[e]] * xr[ZK[e]];
                if (ZG[e]) z[ZSl[e]] += p; else z[ZSl[e]] -= p;
            }
            float* pz = &sm[OFF_Z + b * ZES + (m & 7) * 44];
            #pragma unroll
            for (int s = 0; s < 44; s += 4)
                *(float4*)&pz[s] = make_float4(z[s], z[s+1], z[s+2], z[s+3]);
        }
        __syncthreads();
        #pragma unroll
        for (int nl = 0; nl < 8; ++nl) {
            const int n = c * 8 + nl;
            const float* pw = &w_gp[(m*16+n)*20];                     // uniform -> SGPRs
            float wg[20];
            #pragma unroll
            for (int s = 0; s < 20; s += 4) {
                const float4 u = *(const float4*)&pw[s];
                wg[s]=u.x; wg[s+1]=u.y; wg[s+2]=u.z; wg[s+3]=u.w;
            }
            const float* pz = &sm[OFF_Z + b * ZES + nl * 44];
            #pragma unroll
            for (int s4 = 0; s4 < 11; ++s4) {                         // stream z: no zr[44]
                const float4 u = *(const float4*)&pz[s4*4];
                const int s0 = s4*4;
                gp[CJ[s0+0]] += wg[CP[s0+0]] * u.x;
                gp[CJ[s0+1]] += wg[CP[s0+1]] * u.y;
                gp[CJ[s0+2]] += wg[CP[s0+2]] * u.z;
                gp[CJ[s0+3]] += wg[CP[s0+3]] * u.w;
            }
        }
        __syncthreads();
    }

    // ---------- attended = (left + b_left + gp) / sqrt(2); overwrite X rows with att ----------
    float att[8];
    lf[0] += b_left[m];                                               // uniform
    #pragma unroll
    for (int i = 0; i < 8; ++i) att[i] = (lf[i] + gp[i]) * 0.70710678118654752f;
    *(float4*)&sm[OFF_X + b * XS + m * 8]     = make_float4(att[0],att[1],att[2],att[3]);
    *(float4*)&sm[OFF_X + b * XS + m * 8 + 4] = make_float4(att[4],att[5],att[6],att[7]);
    __syncthreads();

    // ---------- phase D: up -> silu -> down, in 2 chunks of 32 m2 (h[2][8] live) ----------
    float oacc[8] = {0,0,0,0,0,0,0,0};
    #pragma unroll
    for (int ch = 0; ch < 2; ++ch) {
        if (ch) __syncthreads();        // protect H region from previous chunk's reads
        float h0[8] = {0,0,0,0,0,0,0,0};
        float h1[8] = {0,0,0,0,0,0,0,0};
        const int m2a = ch*32 + m;
        const int m2b = ch*32 + 16 + m;
        {
            const float* sa = &sm[OFF_X + b * XS];
            #pragma unroll
            for (int n = 0; n < 16; ++n) {
                const float4 aa = *(const float4*)&sa[n*8];
                const float4 ab = *(const float4*)&sa[n*8+4];
                const float4 wA = *(const float4*)&w_up[(m2a*16+n)*4];   // uniform
                const float4 wB = *(const float4*)&w_up[(m2b*16+n)*4];   // uniform
                h0[0]+=aa.x*wA.x; h0[1]+=aa.y*wA.y; h0[2]+=aa.z*wA.y; h0[3]+=aa.w*wA.y;
                h0[4]+=ab.x*wA.z; h0[5]+=ab.y*wA.z; h0[6]+=ab.z*wA.z; h0[7]+=ab.w*wA.w;
                h1[0]+=aa.x*wB.x; h1[1]+=aa.y*wB.y; h1[2]+=aa.z*wB.y; h1[3]+=aa.w*wB.y;
                h1[4]+=ab.x*wB.z; h1[5]+=ab.y*wB.z; h1[6]+=ab.z*wB.z; h1[7]+=ab.w*wB.w;
            }
        }
        #pragma unroll
        for (int qq = 0; qq < 2; ++qq) {
            float* hh = qq ? h1 : h0;
            const int m2 = qq ? m2b : m2a;
            hh[0] += b_up[m2];                                        // uniform
            const float inv0 = hh[0];
            const float inv1 = hh[1]*hh[1] + hh[2]*hh[2] + hh[3]*hh[3];
            const float inv2 = hh[4]*hh[4] + hh[5]*hh[5] + hh[6]*hh[6];
            const float inv3 = hh[7]*hh[7];
            const float4 a4 = *(const float4*)&a_act[m2*4];           // uniform
            const float4 b4 = *(const float4*)&b_act[m2*4];           // uniform
            const float g0 = sigmoidf_(a4.x*inv0 + b4.x);
            const float g1 = sigmoidf_(a4.y*inv1 + b4.y);
            const float g2 = sigmoidf_(a4.z*inv2 + b4.z);
            const float g3 = sigmoidf_(a4.w*inv3 + b4.w);
            hh[0]*=g0; hh[1]*=g1; hh[2]*=g1; hh[3]*=g1;
            hh[4]*=g2; hh[5]*=g2; hh[6]*=g2; hh[7]*=g3;
            float* ph = &sm[OFF_Z + b * HES + (m + qq*16) * 8];
            *(float4*)&ph[0] = make_float4(hh[0],hh[1],hh[2],hh[3]);
            *(float4*)&ph[4] = make_float4(hh[4],hh[5],hh[6],hh[7]);
        }
        __syncthreads();
        #pragma unroll
        for (int s = 0; s < 32; ++s) {
            const float* pr = &sm[OFF_Z + b * HES + s * 8];
            const float4 ha = *(const float4*)&pr[0];
            const float4 hb = *(const float4*)&pr[4];
            const float4 w  = *(const float4*)&w_down[(m*64 + ch*32 + s)*4];  // uniform
            oacc[0]+=ha.x*w.x; oacc[1]+=ha.y*w.y; oacc[2]+=ha.z*w.y; oacc[3]+=ha.w*w.y;
            oacc[4]+=hb.x*w.z; oacc[5]+=hb.y*w.z; oacc[6]+=hb.z*w.z; oacc[7]+=hb.w*w.w;
        }
    }

    // ---------- epilogue: out = attended + down + b_down; bounce via LDS for dense stores ----------
    __syncthreads();                    // down-reads of H done before overwriting X? (X != H, but keep att rows consistent)
    oacc[0] += b_down[m];                                             // uniform
    *(float4*)&sm[OFF_X + b * XS + m * 8]     = make_float4(att[0]+oacc[0], att[1]+oacc[1],
                                                            att[2]+oacc[2], att[3]+oacc[3]);
    *(float4*)&sm[OFF_X + b * XS + m * 8 + 4] = make_float4(att[4]+oacc[4], att[5]+oacc[5],
                                                            att[6]+oacc[6], att[7]+oacc[7]);
    __syncthreads();
    {
        float4* og = (float4*)outg + (size_t)g * 2048;
        #pragma unroll
        for (int r = 0; r < 2; ++r) {
            const int idx = r * 1024 + t;
            const int el = idx >> 5, off = idx & 31;
            og[idx] = *(const float4*)&sm[OFF_X + el * XS + off * 4];
        }
    }
}

extern "C" void kernel_launch(void* const* d_in, const int* in_sizes, int n_in,
                              void* d_out, int out_size, void* d_ws, size_t ws_size,
                              hipStream_t stream) {
    const float* x       = (const float*)d_in[0];
    const float* w_right = (const float*)d_in[1];
    const float* a_norm  = (const float*)d_in[2];
    const float* w_gp    = (const float*)d_in[3];
    const float* w_left  = (const float*)d_in[4];
    const float* b_left  = (const float*)d_in[5];
    const float* w_up    = (const float*)d_in[6];
    const float* b_up    = (const float*)d_in[7];
    const float* a_act   = (const float*)d_in[8];
    const float* b_act   = (const float*)d_in[9];
    const float* w_down  = (const float*)d_in[10];
    const float* b_down  = (const float*)d_in[11];
    float* out = (float*)d_out;

    const int B = in_sizes[0] / 128;        // 65536
    const int ngroups = B / 64;             // 1024 blocks

    (void)hipFuncSetAttribute((const void*)mv_block_kernel,
                              hipFuncAttributeMaxDynamicSharedMemorySize, SMEM_BYTES);
    mv_block_kernel<<<ngroups, TPB, SMEM_BYTES, stream>>>(
        x, w_right, a_norm, w_gp, w_left, b_left,
        w_up, b_up, a_act, b_act, w_down, b_down, out);
}

// Round 4
// 192.101 us; speedup vs baseline: 7.5521x; 4.6192x over previous
//
#include <hip/hip_runtime.h>
#include <math.h>

#define TPB 512
#define XS    132           // element row stride (dwords); 16B-aligned rows, gcd(132,32)=4
#define OFF_X  0            // [64][132] x -> attended -> out
#define OFF_XR 8448         // [64][132] normalized xr; reused as H (16 m2 x 8 = 128 <= 132)
#define SMEM_FLOATS 16896
#define SMEM_BYTES  (SMEM_FLOATS * 4)   // 67584 B -> 2 blocks/CU

// ---- Cl(3,0): slot s (0..43) of the GP pair-sum, inverted from verified ZSl/ZG tables ----
// slot value t_s = sum of up to 3 signed products x[i]*xr[k]; gp[CJ[s]] += w_gp[CP[s]] * t_s
constexpr int SCNT[44] = {1,1,1,1,1,1,1,1, 3,1,1,1, 2,2,2,2,2,2, 1,1,1, 3,
                          3, 2,2,2, 1,1,1,1,1,1, 2,2,2, 3, 1,1,1,1,1,1,1,1};
constexpr int T1I[44] = {0,0,0,0,0,0,0,0, 1,1,2,3, 2,1,1,1,1,2, 3,2,1, 1,
                         4, 4,4,5, 6,5,4,4,5,6, 5,4,4, 4, 7,7,7,7,7,7,7,7};
constexpr int T1K[44] = {0,1,2,3,4,5,6,7, 1,0,0,0, 4,4,5,2,3,3, 7,7,7, 6,
                         4, 2,1,1, 7,7,7,0,0,0, 6,6,5, 3, 7,6,5,4,3,2,1,0};
constexpr int T1S[44] = {1,1,1,1,1,1,1,1, 1,1,1,1, 0,1,1,1,1,1, 1,0,1, 1,
                         0, 1,0,0, 0,1,0,1,1,1, 0,1,0, 1, 0,0,1,0,1,0,1,1};
constexpr int T2I[44] = {0,0,0,0,0,0,0,0, 2,0,0,0, 3,3,2,2,3,3, 0,0,0, 2,
                         5, 5,6,6, 0,0,0,0,0,0, 6,6,5, 5, 0,0,0,0,0,0,0,0};
constexpr int T2K[44] = {0,0,0,0,0,0,0,0, 2,0,0,0, 5,6,6,1,1,2, 0,0,0, 5,
                         5, 3,3,2, 0,0,0,0,0,0, 5,4,4, 2, 0,0,0,0,0,0,0,0};
constexpr int T2S[44] = {1,1,1,1,1,1,1,1, 1,1,1,1, 0,0,1,0,0,0, 1,1,1, 0,
                         0, 1,1,0, 1,1,1,1,1,1, 1,0,1, 0, 1,1,1,1,1,1,1,1};
constexpr int T3I[44] = {0,0,0,0,0,0,0,0, 3,0,0,0, 0,0,0,0,0,0, 0,0,0, 3,
                         6, 0,0,0, 0,0,0,0,0,0, 0,0,0, 6, 0,0,0,0,0,0,0,0};
constexpr int T3K[44] = {0,0,0,0,0,0,0,0, 3,0,0,0, 0,0,0,0,0,0, 0,0,0, 4,
                         6, 0,0,0, 0,0,0,0,0,0, 0,0,0, 1, 0,0,0,0,0,0,0,0};
constexpr int T3S[44] = {1,1,1,1,1,1,1,1, 1,1,1,1, 1,1,1,1,1,1, 1,1,1, 1,
                         0, 1,1,1, 1,1,1,1,1,1, 1,1,1, 1, 1,1,1,1,1,1,1,1};
// slot -> path index (into w_gp[...,20]) and output blade j (verified rounds 1-3)
constexpr int CP[44] = {
    0, 1,1,1, 2,2,2, 3,
    4, 5,5,5, 6,6,6, 7,7,7, 8,8,8, 9,
    10, 11,11,11, 12,12,12, 13,13,13, 14,14,14, 15,
    16, 17,17,17, 18,18,18, 19};
constexpr int CJ[44] = {
    0, 1,2,3, 4,5,6, 7,
    0, 1,2,3, 1,2,3, 4,5,6, 4,5,6, 7,
    0, 1,2,3, 1,2,3, 4,5,6, 4,5,6, 7,
    0, 1,2,3, 4,5,6, 7};

__device__ __forceinline__ float sigmoidf_(float v) {
    return __builtin_amdgcn_rcpf(1.0f + __expf(-v));
}

__global__ __launch_bounds__(TPB, 2)
void mv_block_kernel(const float* __restrict__ xg,
                     const float* __restrict__ w_right,
                     const float* __restrict__ a_norm,
                     const float* __restrict__ w_gp,
                     const float* __restrict__ w_left,
                     const float* __restrict__ b_left,
                     const float* __restrict__ w_up,
                     const float* __restrict__ b_up,
                     const float* __restrict__ a_act,
                     const float* __restrict__ b_act,
                     const float* __restrict__ w_down,
                     const float* __restrict__ b_down,
                     float* __restrict__ outg)
{
    extern __shared__ float sm[];
    const int t = threadIdx.x;
    const int b = t & 63;                                   // lane = batch element
    const int w = __builtin_amdgcn_readfirstlane(t >> 6);   // wave 0..7 (uniform)
    const int mA = w, mB = w + 8;                           // two channels per wave
    const int g = blockIdx.x;

    // ---------- stage x (coalesced) ----------
    {
        const float4* xs = (const float4*)xg + (size_t)g * 2048;
        #pragma unroll
        for (int r = 0; r < 4; ++r) {
            const int idx = r * TPB + t;
            const float4 v = xs[idx];
            const int el = idx >> 5, off = idx & 31;
            *(float4*)&sm[OFF_X + el * XS + off * 4] = v;
        }
    }
    __syncthreads();

    // ---------- phase A: right-linear (2 ch) + left-linear (2 ch); weights in SGPRs ----------
    float xrA[8] = {0,0,0,0,0,0,0,0}, xrB[8] = {0,0,0,0,0,0,0,0};
    float lfA[8] = {0,0,0,0,0,0,0,0}, lfB[8] = {0,0,0,0,0,0,0,0};
    {
        const float* sx = &sm[OFF_X + b * XS];
        #pragma unroll 1
        for (int n = 0; n < 16; ++n) {
            const float4 xa = *(const float4*)&sx[n*8];
            const float4 xb = *(const float4*)&sx[n*8+4];
            const float4 wa = *(const float4*)&w_right[(mA*16+n)*4];
            const float4 wb = *(const float4*)&w_right[(mB*16+n)*4];
            const float4 va = *(const float4*)&w_left [(mA*16+n)*4];
            const float4 vb = *(const float4*)&w_left [(mB*16+n)*4];
            xrA[0]+=xa.x*wa.x; xrA[1]+=xa.y*wa.y; xrA[2]+=xa.z*wa.y; xrA[3]+=xa.w*wa.y;
            xrA[4]+=xb.x*wa.z; xrA[5]+=xb.y*wa.z; xrA[6]+=xb.z*wa.z; xrA[7]+=xb.w*wa.w;
            xrB[0]+=xa.x*wb.x; xrB[1]+=xa.y*wb.y; xrB[2]+=xa.z*wb.y; xrB[3]+=xa.w*wb.y;
            xrB[4]+=xb.x*wb.z; xrB[5]+=xb.y*wb.z; xrB[6]+=xb.z*wb.z; xrB[7]+=xb.w*wb.w;
            lfA[0]+=xa.x*va.x; lfA[1]+=xa.y*va.y; lfA[2]+=xa.z*va.y; lfA[3]+=xa.w*va.y;
            lfA[4]+=xb.x*va.z; lfA[5]+=xb.y*va.z; lfA[6]+=xb.z*va.z; lfA[7]+=xb.w*va.w;
            lfB[0]+=xa.x*vb.x; lfB[1]+=xa.y*vb.y; lfB[2]+=xa.z*vb.y; lfB[3]+=xa.w*vb.y;
            lfB[4]+=xb.x*vb.z; lfB[5]+=xb.y*vb.z; lfB[6]+=xb.z*vb.z; lfB[7]+=xb.w*vb.w;
        }
    }

    // ---------- phase B: gated per-grade normalization (both channels, in registers) ----------
    #pragma unroll
    for (int q = 0; q < 2; ++q) {
        float* xr = q ? xrB : xrA;
        const int m = q ? mB : mA;
        const float q0 = xr[0]*xr[0];
        const float q1 = xr[1]*xr[1] + xr[2]*xr[2] + xr[3]*xr[3];
        const float q2 = xr[4]*xr[4] + xr[5]*xr[5] + xr[6]*xr[6];
        const float q3 = xr[7]*xr[7];
        const float4 an = *(const float4*)&a_norm[m*4];
        const float i0 = __builtin_amdgcn_rcpf(sigmoidf_(an.x)*(sqrtf(q0)-1.0f)+1.0f + 1e-6f);
        const float i1 = __builtin_amdgcn_rcpf(sigmoidf_(an.y)*(sqrtf(q1)-1.0f)+1.0f + 1e-6f);
        const float i2 = __builtin_amdgcn_rcpf(sigmoidf_(an.z)*(sqrtf(q2)-1.0f)+1.0f + 1e-6f);
        const float i3 = __builtin_amdgcn_rcpf(sigmoidf_(an.w)*(sqrtf(q3)-1.0f)+1.0f + 1e-6f);
        xr[0]*=i0; xr[1]*=i1; xr[2]*=i1; xr[3]*=i1;
        xr[4]*=i2; xr[5]*=i2; xr[6]*=i2; xr[7]*=i3;
    }
    *(float4*)&sm[OFF_XR + b*XS + mA*8]     = make_float4(xrA[0],xrA[1],xrA[2],xrA[3]);
    *(float4*)&sm[OFF_XR + b*XS + mA*8 + 4] = make_float4(xrA[4],xrA[5],xrA[6],xrA[7]);
    *(float4*)&sm[OFF_XR + b*XS + mB*8]     = make_float4(xrB[0],xrB[1],xrB[2],xrB[3]);
    *(float4*)&sm[OFF_XR + b*XS + mB*8 + 4] = make_float4(xrB[4],xrB[5],xrB[6],xrB[7]);
    __syncthreads();

    // ---------- phase C: direct geometric product; products shared across the wave's 2 channels ----------
    float gpA[8] = {0,0,0,0,0,0,0,0}, gpB[8] = {0,0,0,0,0,0,0,0};
    {
        #pragma unroll 1
        for (int n = 0; n < 16; ++n) {
            float xv[8], rv[8];
            { const float4 u = *(const float4*)&sm[OFF_X  + b*XS + n*8];   xv[0]=u.x; xv[1]=u.y; xv[2]=u.z; xv[3]=u.w; }
            { const float4 u = *(const float4*)&sm[OFF_X  + b*XS + n*8+4]; xv[4]=u.x; xv[5]=u.y; xv[6]=u.z; xv[7]=u.w; }
            { const float4 u = *(const float4*)&sm[OFF_XR + b*XS + n*8];   rv[0]=u.x; rv[1]=u.y; rv[2]=u.z; rv[3]=u.w; }
            { const float4 u = *(const float4*)&sm[OFF_XR + b*XS + n*8+4]; rv[4]=u.x; rv[5]=u.y; rv[6]=u.z; rv[7]=u.w; }
            const float* wa = &w_gp[(mA*16+n)*20];     // uniform -> SGPRs
            const float* wb = &w_gp[(mB*16+n)*20];     // uniform -> SGPRs
            #pragma unroll
            for (int s = 0; s < 44; ++s) {
                float tz = T1S[s] ? xv[T1I[s]]*rv[T1K[s]] : -(xv[T1I[s]]*rv[T1K[s]]);
                if (SCNT[s] > 1) tz = T2S[s] ? fmaf(xv[T2I[s]], rv[T2K[s]], tz)
                                             : fmaf(-xv[T2I[s]], rv[T2K[s]], tz);
                if (SCNT[s] > 2) tz = T3S[s] ? fmaf(xv[T3I[s]], rv[T3K[s]], tz)
                                             : fmaf(-xv[T3I[s]], rv[T3K[s]], tz);
                gpA[CJ[s]] = fmaf(wa[CP[s]], tz, gpA[CJ[s]]);
                gpB[CJ[s]] = fmaf(wb[CP[s]], tz, gpB[CJ[s]]);
            }
        }
    }
    __syncthreads();   // all C reads of X/XR done before att overwrites X

    // ---------- attended = (left + b_left + gp)/sqrt(2); keep in regs AND write to X ----------
    float attA[8], attB[8];
    lfA[0] += b_left[mA];
    lfB[0] += b_left[mB];
    #pragma unroll
    for (int i = 0; i < 8; ++i) {
        attA[i] = (lfA[i] + gpA[i]) * 0.70710678118654752f;
        attB[i] = (lfB[i] + gpB[i]) * 0.70710678118654752f;
    }
    *(float4*)&sm[OFF_X + b*XS + mA*8]     = make_float4(attA[0],attA[1],attA[2],attA[3]);
    *(float4*)&sm[OFF_X + b*XS + mA*8 + 4] = make_float4(attA[4],attA[5],attA[6],attA[7]);
    *(float4*)&sm[OFF_X + b*XS + mB*8]     = make_float4(attB[0],attB[1],attB[2],attB[3]);
    *(float4*)&sm[OFF_X + b*XS + mB*8 + 4] = make_float4(attB[4],attB[5],attB[6],attB[7]);
    __syncthreads();

    // ---------- phase D: up -> silu -> down, 4 chunks of 16 m2; H reuses XR region ----------
    float oaccA[8] = {0,0,0,0,0,0,0,0}, oaccB[8] = {0,0,0,0,0,0,0,0};
    #pragma unroll 1
    for (int ch = 0; ch < 4; ++ch) {
        const int m2a = ch*16 + w;
        const int m2b = ch*16 + 8 + w;
        float h0[8] = {0,0,0,0,0,0,0,0}, h1[8] = {0,0,0,0,0,0,0,0};
        {
            const float* sa = &sm[OFF_X + b * XS];
            #pragma unroll 1
            for (int n = 0; n < 16; ++n) {
                const float4 aa = *(const float4*)&sa[n*8];
                const float4 ab = *(const float4*)&sa[n*8+4];
                const float4 wA = *(const float4*)&w_up[(m2a*16+n)*4];   // uniform
                const float4 wB = *(const float4*)&w_up[(m2b*16+n)*4];   // uniform
                h0[0]+=aa.x*wA.x; h0[1]+=aa.y*wA.y; h0[2]+=aa.z*wA.y; h0[3]+=aa.w*wA.y;
                h0[4]+=ab.x*wA.z; h0[5]+=ab.y*wA.z; h0[6]+=ab.z*wA.z; h0[7]+=ab.w*wA.w;
                h1[0]+=aa.x*wB.x; h1[1]+=aa.y*wB.y; h1[2]+=aa.z*wB.y; h1[3]+=aa.w*wB.y;
                h1[4]+=ab.x*wB.z; h1[5]+=ab.y*wB.z; h1[6]+=ab.z*wB.z; h1[7]+=ab.w*wB.w;
            }
        }
        #pragma unroll
        for (int qq = 0; qq < 2; ++qq) {
            float* hh = qq ? h1 : h0;
            const int m2 = qq ? m2b : m2a;
            hh[0] += b_up[m2];
            const float inv0 = hh[0];
            const float inv1 = hh[1]*hh[1] + hh[2]*hh[2] + hh[3]*hh[3];
            const float inv2 = hh[4]*hh[4] + hh[5]*hh[5] + hh[6]*hh[6];
            const float inv3 = hh[7]*hh[7];
            const float4 a4 = *(const float4*)&a_act[m2*4];
            const float4 b4 = *(const float4*)&b_act[m2*4];
            const float g0 = sigmoidf_(a4.x*inv0 + b4.x);
            const float g1 = sigmoidf_(a4.y*inv1 + b4.y);
            const float g2 = sigmoidf_(a4.z*inv2 + b4.z);
            const float g3 = sigmoidf_(a4.w*inv3 + b4.w);
            hh[0]*=g0; hh[1]*=g1; hh[2]*=g1; hh[3]*=g1;
            hh[4]*=g2; hh[5]*=g2; hh[6]*=g2; hh[7]*=g3;
        }
        __syncthreads();   // previous chunk's H reads complete before overwrite
        *(float4*)&sm[OFF_XR + b*XS + w*8]       = make_float4(h0[0],h0[1],h0[2],h0[3]);
        *(float4*)&sm[OFF_XR + b*XS + w*8 + 4]   = make_float4(h0[4],h0[5],h0[6],h0[7]);
        *(float4*)&sm[OFF_XR + b*XS + (w+8)*8]   = make_float4(h1[0],h1[1],h1[2],h1[3]);
        *(float4*)&sm[OFF_XR + b*XS + (w+8)*8+4] = make_float4(h1[4],h1[5],h1[6],h1[7]);
        __syncthreads();   // H visible
        #pragma unroll 1
        for (int s = 0; s < 16; ++s) {
            const float* pr = &sm[OFF_XR + b*XS + s*8];
            const float4 ha = *(const float4*)&pr[0];
            const float4 hb = *(const float4*)&pr[4];
            const float4 wdA = *(const float4*)&w_down[(mA*64 + ch*16 + s)*4];  // uniform
            const float4 wdB = *(const float4*)&w_down[(mB*64 + ch*16 + s)*4];  // uniform
            oaccA[0]+=ha.x*wdA.x; oaccA[1]+=ha.y*wdA.y; oaccA[2]+=ha.z*wdA.y; oaccA[3]+=ha.w*wdA.y;
            oaccA[4]+=hb.x*wdA.z; oaccA[5]+=hb.y*wdA.z; oaccA[6]+=hb.z*wdA.z; oaccA[7]+=hb.w*wdA.w;
            oaccB[0]+=ha.x*wdB.x; oaccB[1]+=ha.y*wdB.y; oaccB[2]+=ha.z*wdB.y; oaccB[3]+=ha.w*wdB.y;
            oaccB[4]+=hb.x*wdB.z; oaccB[5]+=hb.y*wdB.z; oaccB[6]+=hb.z*wdB.z; oaccB[7]+=hb.w*wdB.w;
        }
    }

    // ---------- epilogue: out = attended + down + b_down; bounce via X for dense stores ----------
    oaccA[0] += b_down[mA];
    oaccB[0] += b_down[mB];
    *(float4*)&sm[OFF_X + b*XS + mA*8]     = make_float4(attA[0]+oaccA[0], attA[1]+oaccA[1],
                                                         attA[2]+oaccA[2], attA[3]+oaccA[3]);
    *(float4*)&sm[OFF_X + b*XS + mA*8 + 4] = make_float4(attA[4]+oaccA[4], attA[5]+oaccA[5],
                                                         attA[6]+oaccA[6], attA[7]+oaccA[7]);
    *(float4*)&sm[OFF_X + b*XS + mB*8]     = make_float4(attB[0]+oaccB[0], attB[1]+oaccB[1],
                                                         attB[2]+oaccB[2], attB[3]+oaccB[3]);
    *(float4*)&sm[OFF_X + b*XS + mB*8 + 4] = make_float4(attB[4]+oaccB[4], attB[5]+oaccB[5],
                                                         attB[6]+oaccB[6], attB[7]+oaccB[7]);
    __syncthreads();
    {
        float4* og = (float4*)outg + (size_t)g * 2048;
        #pragma unroll
        for (int r = 0; r < 4; ++r) {
            const int idx = r * TPB + t;
            const int el = idx >> 5, off = idx & 31;
            og[idx] = *(const float4*)&sm[OFF_X + el * XS + off * 4];
        }
    }
}

extern "C" void kernel_launch(void* const* d_in, const int* in_sizes, int n_in,
                              void* d_out, int out_size, void* d_ws, size_t ws_size,
                              hipStream_t stream) {
    const float* x       = (const float*)d_in[0];
    const float* w_right = (const float*)d_in[1];
    const float* a_norm  = (const float*)d_in[2];
    const float* w_gp    = (const float*)d_in[3];
    const float* w_left  = (const float*)d_in[4];
    const float* b_left  = (const float*)d_in[5];
    const float* w_up    = (const float*)d_in[6];
    const float* b_up    = (const float*)d_in[7];
    const float* a_act   = (const float*)d_in[8];
    const float* b_act   = (const float*)d_in[9];
    const float* w_down  = (const float*)d_in[10];
    const float* b_down  = (const float*)d_in[11];
    float* out = (float*)d_out;

    const int B = in_sizes[0] / 128;        // 65536
    const int nblocks = B / 64;             // 1024

    (void)hipFuncSetAttribute((const void*)mv_block_kernel,
                              hipFuncAttributeMaxDynamicSharedMemorySize, SMEM_BYTES);
    mv_block_kernel<<<nblocks, TPB, SMEM_BYTES, stream>>>(
        x, w_right, a_norm, w_gp, w_left, b_left,
        w_up, b_up, a_act, b_act, w_down, b_down, out);
}

// Round 5
// 190.221 us; speedup vs baseline: 7.6267x; 1.0099x over previous
//
#include <hip/hip_runtime.h>
#include <hip/hip_bf16.h>
#include <math.h>

#define TPB 512
#define XS    132           // f32 X region el-stride (dwords); also epilogue scratch (needs >=128)
#define OFF_X  0            // [64][132] f32: x -> attended -> out scratch
#define OFF_XR 8448         // [64][68]  dwords used as bf16 pairs: xr, later h (16 rows x 1 uint4)
#define XRU4   2112         // OFF_XR/4 : uint4 index of XR region
#define SMEM_FLOATS (8448 + 4352)       // 12800 dwords = 51200 B -> 3 blocks/CU
#define SMEM_BYTES  (SMEM_FLOATS * 4)

// ---- Cl(3,0): slot s (0..43) of the GP pair-sum (verified round 4) ----
constexpr int SCNT[44] = {1,1,1,1,1,1,1,1, 3,1,1,1, 2,2,2,2,2,2, 1,1,1, 3,
                          3, 2,2,2, 1,1,1,1,1,1, 2,2,2, 3, 1,1,1,1,1,1,1,1};
constexpr int T1I[44] = {0,0,0,0,0,0,0,0, 1,1,2,3, 2,1,1,1,1,2, 3,2,1, 1,
                         4, 4,4,5, 6,5,4,4,5,6, 5,4,4, 4, 7,7,7,7,7,7,7,7};
constexpr int T1K[44] = {0,1,2,3,4,5,6,7, 1,0,0,0, 4,4,5,2,3,3, 7,7,7, 6,
                         4, 2,1,1, 7,7,7,0,0,0, 6,6,5, 3, 7,6,5,4,3,2,1,0};
constexpr int T1S[44] = {1,1,1,1,1,1,1,1, 1,1,1,1, 0,1,1,1,1,1, 1,0,1, 1,
                         0, 1,0,0, 0,1,0,1,1,1, 0,1,0, 1, 0,0,1,0,1,0,1,1};
constexpr int T2I[44] = {0,0,0,0,0,0,0,0, 2,0,0,0, 3,3,2,2,3,3, 0,0,0, 2,
                         5, 5,6,6, 0,0,0,0,0,0, 6,6,5, 5, 0,0,0,0,0,0,0,0};
constexpr int T2K[44] = {0,0,0,0,0,0,0,0, 2,0,0,0, 5,6,6,1,1,2, 0,0,0, 5,
                         5, 3,3,2, 0,0,0,0,0,0, 5,4,4, 2, 0,0,0,0,0,0,0,0};
constexpr int T2S[44] = {1,1,1,1,1,1,1,1, 1,1,1,1, 0,0,1,0,0,0, 1,1,1, 0,
                         0, 1,1,0, 1,1,1,1,1,1, 1,0,1, 0, 1,1,1,1,1,1,1,1};
constexpr int T3I[44] = {0,0,0,0,0,0,0,0, 3,0,0,0, 0,0,0,0,0,0, 0,0,0, 3,
                         6, 0,0,0, 0,0,0,0,0,0, 0,0,0, 6, 0,0,0,0,0,0,0,0};
constexpr int T3K[44] = {0,0,0,0,0,0,0,0, 3,0,0,0, 0,0,0,0,0,0, 0,0,0, 4,
                         6, 0,0,0, 0,0,0,0,0,0, 0,0,0, 1, 0,0,0,0,0,0,0,0};
constexpr int T3S[44] = {1,1,1,1,1,1,1,1, 1,1,1,1, 1,1,1,1,1,1, 1,1,1, 1,
                         0, 1,1,1, 1,1,1,1,1,1, 1,1,1, 1, 1,1,1,1,1,1,1,1};
constexpr int CP[44] = {
    0, 1,1,1, 2,2,2, 3,
    4, 5,5,5, 6,6,6, 7,7,7, 8,8,8, 9,
    10, 11,11,11, 12,12,12, 13,13,13, 14,14,14, 15,
    16, 17,17,17, 18,18,18, 19};
constexpr int CJ[44] = {
    0, 1,2,3, 4,5,6, 7,
    0, 1,2,3, 1,2,3, 4,5,6, 4,5,6, 7,
    0, 1,2,3, 1,2,3, 4,5,6, 4,5,6, 7,
    0, 1,2,3, 4,5,6, 7};

__device__ __forceinline__ float sigmoidf_(float v) {
    return __builtin_amdgcn_rcpf(1.0f + __expf(-v));
}
__device__ __forceinline__ unsigned pk2(float lo, float hi) {
    __hip_bfloat162 h = __float22bfloat162_rn(make_float2(lo, hi));
    return *reinterpret_cast<unsigned*>(&h);
}
__device__ __forceinline__ uint4 pkrow(const float* v) {
    return make_uint4(pk2(v[0],v[1]), pk2(v[2],v[3]), pk2(v[4],v[5]), pk2(v[6],v[7]));
}
__device__ __forceinline__ void unpkrow(uint4 u, float* v) {
    v[0]=__uint_as_float(u.x<<16); v[1]=__uint_as_float(u.x&0xffff0000u);
    v[2]=__uint_as_float(u.y<<16); v[3]=__uint_as_float(u.y&0xffff0000u);
    v[4]=__uint_as_float(u.z<<16); v[5]=__uint_as_float(u.z&0xffff0000u);
    v[6]=__uint_as_float(u.w<<16); v[7]=__uint_as_float(u.w&0xffff0000u);
}

__global__ __launch_bounds__(TPB, 4)
void mv_block_kernel(const float* __restrict__ xg,
                     const float* __restrict__ w_right,
                     const float* __restrict__ a_norm,
                     const float* __restrict__ w_gp,
                     const float* __restrict__ w_left,
                     const float* __restrict__ b_left,
                     const float* __restrict__ w_up,
                     const float* __restrict__ b_up,
                     const float* __restrict__ a_act,
                     const float* __restrict__ b_act,
                     const float* __restrict__ w_down,
                     const float* __restrict__ b_down,
                     float* __restrict__ outg)
{
    extern __shared__ float sm[];
    uint4* uXR = ((uint4*)sm) + XRU4;
    const int t = threadIdx.x;
    const int b = t & 63;                                   // lane = batch element
    const int w = __builtin_amdgcn_readfirstlane(t >> 6);   // wave 0..7 (uniform)
    const int mA = w, mB = w + 8;                           // two channels per wave
    const int g = blockIdx.x;

    // ---------- stage x (coalesced, f32) ----------
    {
        const float4* xs = (const float4*)xg + (size_t)g * 2048;
        #pragma unroll
        for (int r = 0; r < 4; ++r) {
            const int idx = r * TPB + t;
            const float4 v = xs[idx];
            const int el = idx >> 5, off = idx & 31;
            *(float4*)&sm[OFF_X + el * XS + off * 4] = v;
        }
    }
    __syncthreads();

    // ---------- phase A: right-linear + left-linear (2 channels, weights in SGPRs) ----------
    float xrA[8] = {0,0,0,0,0,0,0,0}, xrB[8] = {0,0,0,0,0,0,0,0};
    float lfA[8] = {0,0,0,0,0,0,0,0}, lfB[8] = {0,0,0,0,0,0,0,0};
    {
        const float* sx = &sm[OFF_X + b * XS];
        #pragma unroll 1
        for (int n = 0; n < 16; ++n) {
            const float4 xa = *(const float4*)&sx[n*8];
            const float4 xb = *(const float4*)&sx[n*8+4];
            const float4 wa = *(const float4*)&w_right[(mA*16+n)*4];
            const float4 wb = *(const float4*)&w_right[(mB*16+n)*4];
            const float4 va = *(const float4*)&w_left [(mA*16+n)*4];
            const float4 vb = *(const float4*)&w_left [(mB*16+n)*4];
            xrA[0]+=xa.x*wa.x; xrA[1]+=xa.y*wa.y; xrA[2]+=xa.z*wa.y; xrA[3]+=xa.w*wa.y;
            xrA[4]+=xb.x*wa.z; xrA[5]+=xb.y*wa.z; xrA[6]+=xb.z*wa.z; xrA[7]+=xb.w*wa.w;
            xrB[0]+=xa.x*wb.x; xrB[1]+=xa.y*wb.y; xrB[2]+=xa.z*wb.y; xrB[3]+=xa.w*wb.y;
            xrB[4]+=xb.x*wb.z; xrB[5]+=xb.y*wb.z; xrB[6]+=xb.z*wb.z; xrB[7]+=xb.w*wb.w;
            lfA[0]+=xa.x*va.x; lfA[1]+=xa.y*va.y; lfA[2]+=xa.z*va.y; lfA[3]+=xa.w*va.y;
            lfA[4]+=xb.x*va.z; lfA[5]+=xb.y*va.z; lfA[6]+=xb.z*va.z; lfA[7]+=xb.w*va.w;
            lfB[0]+=xa.x*vb.x; lfB[1]+=xa.y*vb.y; lfB[2]+=xa.z*vb.y; lfB[3]+=xa.w*vb.y;
            lfB[4]+=xb.x*vb.z; lfB[5]+=xb.y*vb.z; lfB[6]+=xb.z*vb.z; lfB[7]+=xb.w*vb.w;
        }
    }

    // ---------- phase B: gated per-grade normalization ----------
    #pragma unroll
    for (int q = 0; q < 2; ++q) {
        float* xr = q ? xrB : xrA;
        const int m = q ? mB : mA;
        const float q0 = xr[0]*xr[0];
        const float q1 = xr[1]*xr[1] + xr[2]*xr[2] + xr[3]*xr[3];
        const float q2 = xr[4]*xr[4] + xr[5]*xr[5] + xr[6]*xr[6];
        const float q3 = xr[7]*xr[7];
        const float4 an = *(const float4*)&a_norm[m*4];
        const float i0 = __builtin_amdgcn_rcpf(sigmoidf_(an.x)*(sqrtf(q0)-1.0f)+1.0f + 1e-6f);
        const float i1 = __builtin_amdgcn_rcpf(sigmoidf_(an.y)*(sqrtf(q1)-1.0f)+1.0f + 1e-6f);
        const float i2 = __builtin_amdgcn_rcpf(sigmoidf_(an.z)*(sqrtf(q2)-1.0f)+1.0f + 1e-6f);
        const float i3 = __builtin_amdgcn_rcpf(sigmoidf_(an.w)*(sqrtf(q3)-1.0f)+1.0f + 1e-6f);
        xr[0]*=i0; xr[1]*=i1; xr[2]*=i1; xr[3]*=i1;
        xr[4]*=i2; xr[5]*=i2; xr[6]*=i2; xr[7]*=i3;
    }
    uXR[b*17 + mA] = pkrow(xrA);     // xr -> bf16 LDS (1 uint4 per channel)
    uXR[b*17 + mB] = pkrow(xrB);
    __syncthreads();

    // ---------- phase C: direct GP; pair products shared across the wave's 2 channels ----------
    float gpA[8] = {0,0,0,0,0,0,0,0}, gpB[8] = {0,0,0,0,0,0,0,0};
    {
        #pragma unroll 1
        for (int n = 0; n < 16; ++n) {
            float xv[8], rv[8];
            { const float4 u = *(const float4*)&sm[OFF_X + b*XS + n*8];   xv[0]=u.x; xv[1]=u.y; xv[2]=u.z; xv[3]=u.w; }
            { const float4 u = *(const float4*)&sm[OFF_X + b*XS + n*8+4]; xv[4]=u.x; xv[5]=u.y; xv[6]=u.z; xv[7]=u.w; }
            unpkrow(uXR[b*17 + n], rv);
            const float* wa = &w_gp[(mA*16+n)*20];     // uniform -> SGPRs
            const float* wb = &w_gp[(mB*16+n)*20];     // uniform -> SGPRs
            #pragma unroll
            for (int s = 0; s < 44; ++s) {
                float tz = T1S[s] ? xv[T1I[s]]*rv[T1K[s]] : -(xv[T1I[s]]*rv[T1K[s]]);
                if (SCNT[s] > 1) tz = T2S[s] ? fmaf(xv[T2I[s]], rv[T2K[s]], tz)
                                             : fmaf(-xv[T2I[s]], rv[T2K[s]], tz);
                if (SCNT[s] > 2) tz = T3S[s] ? fmaf(xv[T3I[s]], rv[T3K[s]], tz)
                                             : fmaf(-xv[T3I[s]], rv[T3K[s]], tz);
                gpA[CJ[s]] = fmaf(wa[CP[s]], tz, gpA[CJ[s]]);
                gpB[CJ[s]] = fmaf(wb[CP[s]], tz, gpB[CJ[s]]);
            }
        }
    }
    __syncthreads();   // all C reads of X/XR done before att overwrites X

    // ---------- attended = (left + b_left + gp)/sqrt(2); keep f32 in regs AND in X ----------
    float attA[8], attB[8];
    lfA[0] += b_left[mA];
    lfB[0] += b_left[mB];
    #pragma unroll
    for (int i = 0; i < 8; ++i) {
        attA[i] = (lfA[i] + gpA[i]) * 0.70710678118654752f;
        attB[i] = (lfB[i] + gpB[i]) * 0.70710678118654752f;
    }
    *(float4*)&sm[OFF_X + b*XS + mA*8]     = make_float4(attA[0],attA[1],attA[2],attA[3]);
    *(float4*)&sm[OFF_X + b*XS + mA*8 + 4] = make_float4(attA[4],attA[5],attA[6],attA[7]);
    *(float4*)&sm[OFF_X + b*XS + mB*8]     = make_float4(attB[0],attB[1],attB[2],attB[3]);
    *(float4*)&sm[OFF_X + b*XS + mB*8 + 4] = make_float4(attB[4],attB[5],attB[6],attB[7]);
    __syncthreads();

    // ---------- phase D: up -> silu -> down, 4 chunks of 16 m2; h bf16 in XR region ----------
    float oaccA[8] = {0,0,0,0,0,0,0,0}, oaccB[8] = {0,0,0,0,0,0,0,0};
    #pragma unroll 1
    for (int ch = 0; ch < 4; ++ch) {
        const int m2a = ch*16 + w;
        const int m2b = ch*16 + 8 + w;
        float h0[8] = {0,0,0,0,0,0,0,0}, h1[8] = {0,0,0,0,0,0,0,0};
        {
            const float* sa = &sm[OFF_X + b * XS];
            #pragma unroll 1
            for (int n = 0; n < 16; ++n) {
                const float4 aa = *(const float4*)&sa[n*8];
                const float4 ab = *(const float4*)&sa[n*8+4];
                const float4 wA = *(const float4*)&w_up[(m2a*16+n)*4];   // uniform
                const float4 wB = *(const float4*)&w_up[(m2b*16+n)*4];   // uniform
                h0[0]+=aa.x*wA.x; h0[1]+=aa.y*wA.y; h0[2]+=aa.z*wA.y; h0[3]+=aa.w*wA.y;
                h0[4]+=ab.x*wA.z; h0[5]+=ab.y*wA.z; h0[6]+=ab.z*wA.z; h0[7]+=ab.w*wA.w;
                h1[0]+=aa.x*wB.x; h1[1]+=aa.y*wB.y; h1[2]+=aa.z*wB.y; h1[3]+=aa.w*wB.y;
                h1[4]+=ab.x*wB.z; h1[5]+=ab.y*wB.z; h1[6]+=ab.z*wB.z; h1[7]+=ab.w*wB.w;
            }
        }
        #pragma unroll
        for (int qq = 0; qq < 2; ++qq) {
            float* hh = qq ? h1 : h0;
            const int m2 = qq ? m2b : m2a;
            hh[0] += b_up[m2];
            const float inv0 = hh[0];
            const float inv1 = hh[1]*hh[1] + hh[2]*hh[2] + hh[3]*hh[3];
            const float inv2 = hh[4]*hh[4] + hh[5]*hh[5] + hh[6]*hh[6];
            const float inv3 = hh[7]*hh[7];
            const float4 a4 = *(const float4*)&a_act[m2*4];
            const float4 b4 = *(const float4*)&b_act[m2*4];
            const float g0 = sigmoidf_(a4.x*inv0 + b4.x);
            const float g1 = sigmoidf_(a4.y*inv1 + b4.y);
            const float g2 = sigmoidf_(a4.z*inv2 + b4.z);
            const float g3 = sigmoidf_(a4.w*inv3 + b4.w);
            hh[0]*=g0; hh[1]*=g1; hh[2]*=g1; hh[3]*=g1;
            hh[4]*=g2; hh[5]*=g2; hh[6]*=g2; hh[7]*=g3;
        }
        __syncthreads();   // previous chunk's H reads complete before overwrite
        uXR[b*17 + w]     = pkrow(h0);
        uXR[b*17 + 8 + w] = pkrow(h1);
        __syncthreads();   // H visible
        #pragma unroll 1
        for (int s = 0; s < 16; ++s) {
            float hv[8];
            unpkrow(uXR[b*17 + s], hv);
            const float4 wdA = *(const float4*)&w_down[(mA*64 + ch*16 + s)*4];  // uniform
            const float4 wdB = *(const float4*)&w_down[(mB*64 + ch*16 + s)*4];  // uniform
            oaccA[0]+=hv[0]*wdA.x; oaccA[1]+=hv[1]*wdA.y; oaccA[2]+=hv[2]*wdA.y; oaccA[3]+=hv[3]*wdA.y;
            oaccA[4]+=hv[4]*wdA.z; oaccA[5]+=hv[5]*wdA.z; oaccA[6]+=hv[6]*wdA.z; oaccA[7]+=hv[7]*wdA.w;
            oaccB[0]+=hv[0]*wdB.x; oaccB[1]+=hv[1]*wdB.y; oaccB[2]+=hv[2]*wdB.y; oaccB[3]+=hv[3]*wdB.y;
            oaccB[4]+=hv[4]*wdB.z; oaccB[5]+=hv[5]*wdB.z; oaccB[6]+=hv[6]*wdB.z; oaccB[7]+=hv[7]*wdB.w;
        }
    }

    // ---------- epilogue: out = attended + down + b_down (f32, lane-private rows) ----------
    oaccA[0] += b_down[mA];
    oaccB[0] += b_down[mB];
    *(float4*)&sm[OFF_X + b*XS + mA*8]     = make_float4(attA[0]+oaccA[0], attA[1]+oaccA[1],
                                                         attA[2]+oaccA[2], attA[3]+oaccA[3]);
    *(float4*)&sm[OFF_X + b*XS + mA*8 + 4] = make_float4(attA[4]+oaccA[4], attA[5]+oaccA[5],
                                                         attA[6]+oaccA[6], attA[7]+oaccA[7]);
    *(float4*)&sm[OFF_X + b*XS + mB*8]     = make_float4(attB[0]+oaccB[0], attB[1]+oaccB[1],
                                                         attB[2]+oaccB[2], attB[3]+oaccB[3]);
    *(float4*)&sm[OFF_X + b*XS + mB*8 + 4] = make_float4(attB[4]+oaccB[4], attB[5]+oaccB[5],
                                                         attB[6]+oaccB[6], attB[7]+oaccB[7]);
    __syncthreads();
    {
        float4* og = (float4*)outg + (size_t)g * 2048;
        #pragma unroll
        for (int r = 0; r < 4; ++r) {
            const int idx = r * TPB + t;
            const int el = idx >> 5, off = idx & 31;
            og[idx] = *(const float4*)&sm[OFF_X + el * XS + off * 4];
        }
    }
}

extern "C" void kernel_launch(void* const* d_in, const int* in_sizes, int n_in,
                              void* d_out, int out_size, void* d_ws, size_t ws_size,
                              hipStream_t stream) {
    const float* x       = (const float*)d_in[0];
    const float* w_right = (const float*)d_in[1];
    const float* a_norm  = (const float*)d_in[2];
    const float* w_gp    = (const float*)d_in[3];
    const float* w_left  = (const float*)d_in[4];
    const float* b_left  = (const float*)d_in[5];
    const float* w_up    = (const float*)d_in[6];
    const float* b_up    = (const float*)d_in[7];
    const float* a_act   = (const float*)d_in[8];
    const float* b_act   = (const float*)d_in[9];
    const float* w_down  = (const float*)d_in[10];
    const float* b_down  = (const float*)d_in[11];
    float* out = (float*)d_out;

    const int B = in_sizes[0] / 128;        // 65536
    const int nblocks = B / 64;             // 1024

    (void)hipFuncSetAttribute((const void*)mv_block_kernel,
                              hipFuncAttributeMaxDynamicSharedMemorySize, SMEM_BYTES);
    mv_block_kernel<<<nblocks, TPB, SMEM_BYTES, stream>>>(
        x, w_right, a_norm, w_gp, w_left, b_left,
        w_up, b_up, a_act, b_act, w_down, b_down, out);
}